// Round 3
// baseline (671.537 us; speedup 1.0000x reference)
//
#include <hip/hip_runtime.h>
#include <math.h>

typedef unsigned int u32;

// ---------------- ws layout ----------------
//     0: madsum (f32)
//    64: cnt[32]        (zeroed)
//   192: prefix15[32]   (written by hist16 last-block)
//   320: kk2[32]        (written by hist16 last-block)
//   448: scale[32]      (written by compact last-block)
//   576: done16[32]     (zeroed)
//   704: done2[32]      (zeroed)
//  4096: gh16[32*32768] = 4 MB (zeroed)
//  4198400: buf u32[32*8192] = 1 MB
//  5246976: arts uint2[6291456] = 50.33 MB

__device__ __forceinline__ float med3f(float a, float b, float c) {
    return fmaxf(fminf(a, b), fminf(fmaxf(a, b), c));
}
__device__ __forceinline__ float med5f(float a0, float a1, float a2, float a3, float a4) {
    float mn01 = fminf(a0, a1), mx01 = fmaxf(a0, a1);
    float mn34 = fminf(a3, a4), mx34 = fmaxf(a3, a4);
    return med3f(a2, fmaxf(mn01, mn34), fminf(mx01, mx34));
}
__device__ __forceinline__ u32 packbf(float lo, float hi) {
    u32 a = __float_as_uint(lo), b = __float_as_uint(hi);
    a = (a + 0x7FFFu + ((a >> 16) & 1u)) >> 16;
    b = (b + 0x7FFFu + ((b >> 16) & 1u)) >> 16;
    return a | (b << 16);
}
__device__ __forceinline__ u32 aload(const u32* p) {
    return __hip_atomic_load(p, __ATOMIC_RELAXED, __HIP_MEMORY_SCOPE_AGENT);
}

// inclusive scan over 256 threads; wtot is 4-entry LDS; contains internal syncs
__device__ __forceinline__ u32 scan256(u32 v, u32* wtot) {
    int lane = threadIdx.x & 63, wid = threadIdx.x >> 6;
    u32 inc = v;
    #pragma unroll
    for (int off = 1; off < 64; off <<= 1) {
        u32 o = __shfl_up(inc, off);
        if (lane >= off) inc += o;
    }
    __syncthreads();
    if (lane == 63) wtot[wid] = inc;
    __syncthreads();
    for (int w = 0; w < wid; ++w) inc += wtot[w];
    return inc;
}

// ---------------- pass 1: 15-bit MSB histogram + fused select ----------------

__global__ __launch_bounds__(256) void hist16_kernel(
        const float* __restrict__ x, u32* __restrict__ gh, u32* __restrict__ done,
        u32* __restrict__ prefix15, u32* __restrict__ kk2) {
    __shared__ u32 wtot[4];
    __shared__ int amLast;
    __shared__ u32 sWin, sKr;
    int b = blockIdx.x / 24, s = blockIdx.x % 24;
    int t = threadIdx.x;
    const float4* xb = (const float4*)(x + (size_t)b * 196608 + (size_t)s * 8192);
    u32* g = gh + b * 32768;
    #pragma unroll
    for (int j = 0; j < 8; ++j) {
        float4 v = xb[t + j * 256];
        atomicAdd(&g[__float_as_uint(fabsf(v.x)) >> 16], 1u);
        atomicAdd(&g[__float_as_uint(fabsf(v.y)) >> 16], 1u);
        atomicAdd(&g[__float_as_uint(fabsf(v.z)) >> 16], 1u);
        atomicAdd(&g[__float_as_uint(fabsf(v.w)) >> 16], 1u);
    }
    if (t == 0) {
        __threadfence();
        amLast = (atomicAdd(&done[b], 1u) == 23u);
    }
    __syncthreads();
    if (!amLast) return;
    __threadfence();
    // select bin containing rank 98303 among 32768 bins (chunks of 128/thread)
    u32 sum = 0;
    for (int j = 0; j < 128; ++j) sum += aload(&g[t * 128 + j]);
    u32 inc = scan256(sum, wtot);
    u32 exc = inc - sum;
    u32 k = 98303u;   // lower median rank, (196608-1)/2
    if (exc <= k && k < inc) { sWin = (u32)t; sKr = k - exc; }
    __syncthreads();
    u32 chunk = sWin, kr = sKr;
    u32 c = (t < 128) ? aload(&g[chunk * 128 + t]) : 0u;
    u32 inc2 = scan256(c, wtot);
    u32 exc2 = inc2 - c;
    if (t < 128 && exc2 <= kr && kr < inc2) {
        prefix15[b] = chunk * 128 + (u32)t;
        kk2[b] = kr - exc2;
    }
}

// ---------------- pass 2: compact matching values + fused final select ----------------

__global__ __launch_bounds__(256) void compact_kernel(
        const float* __restrict__ x, const u32* __restrict__ prefix15,
        u32* __restrict__ cnt, u32* __restrict__ buf, u32* __restrict__ done,
        const u32* __restrict__ kk2, float* __restrict__ scale) {
    __shared__ u32 wtot[4];
    __shared__ int amLast;
    __shared__ u32 h[256];
    __shared__ u32 sB1, sK;
    int b = blockIdx.x / 24, s = blockIdx.x % 24;
    int t = threadIdx.x;
    u32 pref = prefix15[b];
    const float4* xb = (const float4*)(x + (size_t)b * 196608 + (size_t)s * 8192);
    #pragma unroll
    for (int j = 0; j < 8; ++j) {
        float4 v = xb[t + j * 256];
        float vv[4] = {v.x, v.y, v.z, v.w};
        #pragma unroll
        for (int e = 0; e < 4; ++e) {
            u32 bits = __float_as_uint(fabsf(vv[e]));
            if ((bits >> 16) == pref) {
                u32 i = atomicAdd(&cnt[b], 1u);
                if (i < 8192u)
                    __hip_atomic_store(&buf[b * 8192 + i], bits & 0xFFFFu,
                                       __ATOMIC_RELAXED, __HIP_MEMORY_SCOPE_AGENT);
            }
        }
    }
    if (t == 0) {
        __threadfence();
        amLast = (atomicAdd(&done[b], 1u) == 23u);
    }
    __syncthreads();
    if (!amLast) return;
    __threadfence();
    u32 m = aload(&cnt[b]);
    if (m > 8192u) m = 8192u;
    const u32* vb = buf + b * 8192;
    u32 k = kk2[b];
    // radix: high byte of low16
    h[t] = 0u;
    __syncthreads();
    for (u32 i = t; i < m; i += 256u) atomicAdd(&h[aload(&vb[i]) >> 8], 1u);
    __syncthreads();
    u32 c = h[t];
    u32 inc = scan256(c, wtot);
    u32 exc = inc - c;
    if (exc <= k && k < inc) { sB1 = (u32)t; sK = k - exc; }
    __syncthreads();
    u32 b1 = sB1;
    k = sK;
    h[t] = 0u;
    __syncthreads();
    for (u32 i = t; i < m; i += 256u) {
        u32 vv = aload(&vb[i]);
        if ((vv >> 8) == b1) atomicAdd(&h[vv & 255u], 1u);
    }
    __syncthreads();
    c = h[t];
    inc = scan256(c, wtot);
    exc = inc - c;
    if (exc <= k && k < inc) {
        u32 val = (prefix15[b] << 16) | (b1 << 8) | (u32)t;
        scale[b] = __uint_as_float(val) + 1e-8f;
    }
}

// ---------------- denoise: register-pipelined row sweep ----------------

__device__ __forceinline__ float stageu(float B, float C, float xnB, float& gyp,
                                        int row, float mR, float mL, float lam, float del) {
    float dy = C - B;
    float gy = dy * __builtin_amdgcn_rcpf(del + fabsf(dy));
    if (row >= 255) gy = 0.0f;
    float divy = gy - ((row == 0) ? 0.0f : gyp);
    gyp = gy;
    float Bn = __shfl_down(B, 1);
    float dx = Bn - B;
    float gx = dx * __builtin_amdgcn_rcpf(del + fabsf(dx));
    gx *= mR;
    float gxU = __shfl_up(gx, 1) * mL;
    float t = B - xnB;
    t = fmaf(-lam, (gx - gxU) + divy, t);
    return fmaf(-0.2f, t, B);
}

__global__ __launch_bounds__(256, 8) void denoise_kernel(
        const float* __restrict__ x, const float* __restrict__ scale,
        uint2* __restrict__ arts, float* __restrict__ madsum,
        float4 lam4, float4 del4) {
    int bid = blockIdx.x;
    int img = bid / 20;            // 96 images (b*3+c)
    int t20 = bid % 20;
    int band = t20 % 5;            // 5 column bands
    int q = t20 / 5;               // 0..3
    int tid = threadIdx.x;
    int lane = tid & 63;
    int wid = tid >> 6;
    int seg = q * 4 + wid;         // 16 row segments of 16 rows
    int cb = (band == 4) ? 192 : band * 58;
    int wlo = (band == 0) ? 0 : band * 58 + 3;
    int whi = (band == 4) ? 255 : band * 58 + 60;
    int c = cb + lane;
    bool act = (c >= wlo) && (c <= whi);
    float mR = (c == 255) ? 0.0f : 1.0f;
    float mL = (c == 0) ? 0.0f : 1.0f;
    float sc = scale[img / 3];
    float inv_sc = 1.0f / sc;
    const float* xp = x + (size_t)img * 65536 + c;
    uint2* ap = arts + (size_t)img * 65536 + c;

    float lam[4] = {lam4.x, lam4.y, lam4.z, lam4.w};
    float del[4] = {del4.x, del4.y, del4.z, del4.w};
    float cur1[4], cur2[4], gyp1[4], gyp2[4], gyp3[4];
    #pragma unroll
    for (int v = 0; v < 4; ++v) { cur1[v] = 0.f; cur2[v] = 0.f; gyp1[v] = 0.f; gyp2[v] = 0.f; gyp3[v] = 0.f; }
    float n0 = 0.f, n1 = 0.f, n2 = 0.f;
    int out_lo = seg * 16, out_hi = out_lo + 15;
    int rs = (out_lo >= 3) ? out_lo - 3 : 0;   // 3-row pipeline warm-up
    int rend = out_hi + 3;                      // 3-step flush
    float msum = 0.0f;

    float nl = xp[rs << 8] * inv_sc;
    for (int r = rs; r <= rend; ++r) {
        float nxt = 0.0f;
        if (r < rend && (r + 1) <= 255) nxt = xp[(r + 1) << 8];   // prefetch
        int r1 = r - 1, r2 = r - 2, r3 = r - 3;
        float a[4];
        #pragma unroll
        for (int v = 0; v < 4; ++v) {
            float x1 = stageu(n0,      nl, n0, gyp1[v], r1, mR, mL, lam[v], del[v]);
            float x2 = stageu(cur1[v], x1, n1, gyp2[v], r2, mR, mL, lam[v], del[v]);
            float x3 = stageu(cur2[v], x2, n2, gyp3[v], r3, mR, mL, lam[v], del[v]);
            cur1[v] = x1; cur2[v] = x2; a[v] = x3;
        }
        if (r3 >= out_lo) {   // uniform; r3 <= out_hi by loop bound
            float a1 = a[0] * sc, a2 = a[1] * sc, a3 = a[2] * sc, a4 = a[3] * sc;
            float a0 = n2 * sc;
            if (act) {
                uint2 pk;
                pk.x = packbf(a1, a2);
                pk.y = packbf(a3, a4);
                ap[r3 << 8] = pk;
                float med = med5f(a0, a1, a2, a3, a4);
                float mad = med5f(fabsf(a0 - med), fabsf(a1 - med), fabsf(a2 - med),
                                  fabsf(a3 - med), fabsf(a4 - med));
                msum += mad;
            }
        }
        n2 = n1; n1 = n0; n0 = nl;
        nl = nxt * inv_sc;
    }
    #pragma unroll
    for (int off = 32; off > 0; off >>= 1) msum += __shfl_down(msum, off);
    if (lane == 0) atomicAdd(madsum, msum);
}

// ---------------- fusion ----------------

__global__ __launch_bounds__(256) void fuse_kernel(
        const float* __restrict__ x, const uint2* __restrict__ arts,
        const float* __restrict__ madsum, float* __restrict__ out) {
    int i = blockIdx.x * 256 + threadIdx.x;
    float floorv = 0.1f * (*madsum) * (1.0f / 6291456.0f);
    uint2 pk = arts[i];
    float a0 = x[i];
    float a1 = __uint_as_float(pk.x << 16);
    float a2 = __uint_as_float(pk.x & 0xFFFF0000u);
    float a3 = __uint_as_float(pk.y << 16);
    float a4 = __uint_as_float(pk.y & 0xFFFF0000u);
    float med = med5f(a0, a1, a2, a3, a4);
    float d0 = fabsf(a0 - med), d1 = fabsf(a1 - med), d2 = fabsf(a2 - med);
    float d3 = fabsf(a3 - med), d4 = fabsf(a4 - med);
    float mad = med5f(d0, d1, d2, d3, d4);
    float m = fmaxf(mad, floorv);
    float inv = 0.5f / m;
    float w0 = __expf(-d0 * inv), w1 = __expf(-d1 * inv), w2 = __expf(-d2 * inv);
    float w3 = __expf(-d3 * inv), w4 = __expf(-d4 * inv);
    float swt = w0 + w1 + w2 + w3 + w4;
    float sva = fmaf(w0, a0, fmaf(w1, a1, fmaf(w2, a2, fmaf(w3, a3, w4 * a4))));
    out[i] = sva / (swt + 1e-8f);
}

// ---------------- launch ----------------

extern "C" void kernel_launch(void* const* d_in, const int* in_sizes, int n_in,
                              void* d_out, int out_size, void* d_ws, size_t ws_size,
                              hipStream_t stream) {
    const float* x = (const float*)d_in[0];
    float* out = (float*)d_out;
    char* ws = (char*)d_ws;
    float* madsum  = (float*)ws;
    u32* cnt       = (u32*)(ws + 64);
    u32* prefix15  = (u32*)(ws + 192);
    u32* kk2       = (u32*)(ws + 320);
    float* scale   = (float*)(ws + 448);
    u32* done16    = (u32*)(ws + 576);
    u32* done2     = (u32*)(ws + 704);
    u32* gh16      = (u32*)(ws + 4096);
    u32* buf       = (u32*)(ws + 4198400);
    uint2* arts    = (uint2*)(ws + 5246976);

    // zero madsum/cnt/done flags + 4 MB histogram in one shot
    hipMemsetAsync(ws, 0, 4198400, stream);

    hist16_kernel<<<768, 256, 0, stream>>>(x, gh16, done16, prefix15, kk2);
    compact_kernel<<<768, 256, 0, stream>>>(x, prefix15, cnt, buf, done2, kk2, scale);

    float lamf[4], delf[4];
    for (int i = 0; i < 4; ++i) {
        double lam = 0.025 + 0.05 * (double)i / 3.0;
        lamf[i] = (float)lam;
        delf[i] = (float)(0.01 * sqrt(lam / (0.05 + 1e-8)));
    }
    float4 lam4 = make_float4(lamf[0], lamf[1], lamf[2], lamf[3]);
    float4 del4 = make_float4(delf[0], delf[1], delf[2], delf[3]);

    denoise_kernel<<<1920, 256, 0, stream>>>(x, scale, arts, madsum, lam4, del4);
    fuse_kernel<<<24576, 256, 0, stream>>>(x, arts, madsum, out);
}

// Round 4
// 283.769 us; speedup vs baseline: 2.3665x; 2.3665x over previous
//
#include <hip/hip_runtime.h>
#include <math.h>

typedef unsigned int u32;

#define NPIX 6291456

// ---------------- ws layout ----------------
//      0: madsum f32
//    128: done16[32]
//    256: prefix12[32]
//    384: kk2[32]
//    512: scale[32]
//   1024: cnt[32*32]  (128-B stride per batch counter)
//   8192: gh[32*2048] = 256 KB
// 270336: buf[32*12288] = 1.5 MB
// 1843200: arts uint2[NPIX] = 50.33 MB

__device__ __forceinline__ float med3f(float a, float b, float c) {
    return fmaxf(fminf(a, b), fminf(fmaxf(a, b), c));
}
__device__ __forceinline__ float med5f(float a0, float a1, float a2, float a3, float a4) {
    float mn01 = fminf(a0, a1), mx01 = fmaxf(a0, a1);
    float mn34 = fminf(a3, a4), mx34 = fmaxf(a3, a4);
    return med3f(a2, fmaxf(mn01, mn34), fminf(mx01, mx34));
}
__device__ __forceinline__ u32 packbf(float lo, float hi) {
    u32 a = __float_as_uint(lo), b = __float_as_uint(hi);
    a = (a + 0x7FFFu + ((a >> 16) & 1u)) >> 16;
    b = (b + 0x7FFFu + ((b >> 16) & 1u)) >> 16;
    return a | (b << 16);
}
__device__ __forceinline__ u32 aload(const u32* p) {
    return __hip_atomic_load(p, __ATOMIC_RELAXED, __HIP_MEMORY_SCOPE_AGENT);
}

// inclusive scan over 256 threads; wtot is 4-entry LDS; all threads must call
__device__ __forceinline__ u32 scan256(u32 v, u32* wtot) {
    int lane = threadIdx.x & 63, wid = threadIdx.x >> 6;
    u32 inc = v;
    #pragma unroll
    for (int off = 1; off < 64; off <<= 1) {
        u32 o = __shfl_up(inc, off);
        if (lane >= off) inc += o;
    }
    __syncthreads();
    if (lane == 63) wtot[wid] = inc;
    __syncthreads();
    for (int w = 0; w < wid; ++w) inc += wtot[w];
    return inc;
}

// ---------------- pass A: 11-bit LDS histogram + fused select ----------------

__global__ __launch_bounds__(256) void histA_kernel(
        const float* __restrict__ x, u32* __restrict__ gh, u32* __restrict__ done,
        u32* __restrict__ prefix12, u32* __restrict__ kk2) {
    __shared__ u32 lh[4096];   // 2048 bins x 2 lane-spread sub-bins
    __shared__ u32 wtot[4];
    __shared__ int amLast;
    int b = blockIdx.x / 24, s = blockIdx.x % 24;
    int t = threadIdx.x, lane = t & 63;
    uint4 z = make_uint4(0u, 0u, 0u, 0u);
    #pragma unroll
    for (int j = 0; j < 4; ++j) ((uint4*)lh)[t + j * 256] = z;
    __syncthreads();
    const float4* xb = (const float4*)(x + (size_t)b * 196608 + (size_t)s * 8192);
    u32 sub = (u32)(lane & 1);
    #pragma unroll
    for (int j = 0; j < 8; ++j) {
        float4 v = xb[t + j * 256];
        atomicAdd(&lh[((__float_as_uint(fabsf(v.x)) >> 20) << 1) + sub], 1u);
        atomicAdd(&lh[((__float_as_uint(fabsf(v.y)) >> 20) << 1) + sub], 1u);
        atomicAdd(&lh[((__float_as_uint(fabsf(v.z)) >> 20) << 1) + sub], 1u);
        atomicAdd(&lh[((__float_as_uint(fabsf(v.w)) >> 20) << 1) + sub], 1u);
    }
    __syncthreads();
    u32* g = gh + b * 2048;
    #pragma unroll
    for (int j = 0; j < 8; ++j) {
        int bin = t + j * 256;                    // coalesced merge, ~50 nonzero/block
        u32 c = lh[bin * 2] + lh[bin * 2 + 1];
        if (c) atomicAdd(&g[bin], c);
    }
    __syncthreads();
    if (t == 0) {
        __threadfence();
        amLast = (atomicAdd(&done[b], 1u) == 23u);
    }
    __syncthreads();
    if (!amLast) return;
    __threadfence();
    u32 s8[8], sum = 0;
    #pragma unroll
    for (int j = 0; j < 8; ++j) { s8[j] = aload(&g[t * 8 + j]); sum += s8[j]; }
    u32 inc = scan256(sum, wtot);
    u32 exc = inc - sum;
    u32 k = 98303u;   // lower-median rank, (196608-1)/2
    if (exc <= k && k < inc) {
        u32 kr = k - exc;
        int j = 0;
        while (kr >= s8[j]) { kr -= s8[j]; ++j; }
        prefix12[b] = (u32)(t * 8 + j);
        kk2[b] = kr;
    }
}

// ---------------- pass B: wave-aggregated compaction ----------------

__global__ __launch_bounds__(256) void compactB_kernel(
        const float* __restrict__ x, const u32* __restrict__ prefix12,
        u32* __restrict__ cnt, u32* __restrict__ buf) {
    int b = blockIdx.x / 24, s = blockIdx.x % 24;
    int t = threadIdx.x, lane = t & 63;
    u32 pref = prefix12[b];
    const float4* xb = (const float4*)(x + (size_t)b * 196608 + (size_t)s * 8192);
    u32* cb = &cnt[b * 32];        // 128-B padded counter
    u32* bb = buf + b * 12288;
    #pragma unroll
    for (int j = 0; j < 8; ++j) {
        float4 v = xb[t + j * 256];
        float vv[4] = {v.x, v.y, v.z, v.w};
        u32 val[4]; int m = 0;
        #pragma unroll
        for (int e = 0; e < 4; ++e) {
            u32 bits = __float_as_uint(fabsf(vv[e]));
            if ((bits >> 20) == pref) { val[m] = bits & 0xFFFFFu; ++m; }
        }
        u32 inc = (u32)m;
        #pragma unroll
        for (int off = 1; off < 64; off <<= 1) {
            u32 o = __shfl_up(inc, off);
            if (lane >= off) inc += o;
        }
        u32 tot = __shfl(inc, 63);
        if (tot) {
            u32 base = 0;
            if (lane == 0) base = atomicAdd(cb, tot);   // 1 atomic / wave / group
            base = __shfl(base, 0);
            u32 pos = base + inc - (u32)m;
            for (int q = 0; q < m; ++q)
                if (pos + q < 12288u) bb[pos + q] = val[q];
        }
    }
}

// ---------------- pass C: in-LDS 20-bit radix select, 1 block/batch ----------------

__global__ __launch_bounds__(256) void selectC_kernel(
        const u32* __restrict__ cnt, const u32* __restrict__ buf,
        const u32* __restrict__ prefix12, const u32* __restrict__ kk2,
        float* __restrict__ scale) {
    __shared__ u32 sh[12288];
    __shared__ u32 h[128];
    __shared__ u32 wtot[4];
    __shared__ u32 sPfx, sK;
    int b = blockIdx.x, t = threadIdx.x;
    u32 m = aload(&cnt[b * 32]); if (m > 12288u) m = 12288u;
    const u32* bb = buf + b * 12288;
    for (u32 i = (u32)t; i < m; i += 256u) sh[i] = bb[i];
    if (t == 0) { sPfx = 0u; sK = kk2[b]; }
    __syncthreads();
    const int shf[3] = {13, 6, 0};
    const int wd[3]  = {7, 7, 6};
    const u32 msk[3] = {127u, 127u, 63u};
    #pragma unroll 1
    for (int rd = 0; rd < 3; ++rd) {
        u32 pfx = sPfx, k = sK;
        if (t < 128) h[t] = 0u;
        __syncthreads();
        for (u32 i = (u32)t; i < m; i += 256u) {
            u32 v = sh[i];
            if ((v >> (shf[rd] + wd[rd])) == pfx)
                atomicAdd(&h[(v >> shf[rd]) & msk[rd]], 1u);
        }
        __syncthreads();
        u32 nb = msk[rd] + 1u;
        u32 c = ((u32)t < nb) ? h[t] : 0u;
        u32 inc = scan256(c, wtot);
        u32 exc = inc - c;
        if ((u32)t < nb && exc <= k && k < inc) {
            sPfx = (pfx << wd[rd]) | (u32)t;
            sK = k - exc;
        }
        __syncthreads();
    }
    if (t == 0) scale[b] = __uint_as_float((prefix12[b] << 20) | sPfx) + 1e-8f;
}

// ---------------- denoise: DPP row sweep, 2 cols/thread, no LDS/DS ----------------

__device__ __forceinline__ float dpp_shl1(float v) {   // lane i <- lane i+1
    return __uint_as_float((u32)__builtin_amdgcn_update_dpp(
        0, (int)__float_as_uint(v), 0x130, 0xF, 0xF, true));   // wave_shl:1
}
__device__ __forceinline__ float dpp_shr1(float v) {   // lane i <- lane i-1
    return __uint_as_float((u32)__builtin_amdgcn_update_dpp(
        0, (int)__float_as_uint(v), 0x138, 0xF, 0xF, true));   // wave_shr:1
}
__device__ __forceinline__ float hub(float d, float del) {
    return d * __builtin_amdgcn_rcpf(del + fabsf(d));
}

__device__ __forceinline__ float2 stage2(float2 B, float2 C, float2 xnB, float2& gyp,
                                         int row, float mR1, float mL0,
                                         float lam, float del) {
    float gy0 = hub(C.x - B.x, del);
    float gy1 = hub(C.y - B.y, del);
    if (row >= 255) { gy0 = 0.f; gy1 = 0.f; }              // wave-uniform
    float divy0 = gy0 - ((row == 0) ? 0.f : gyp.x);        // div_y[0] = gy[0]
    float divy1 = gy1 - ((row == 0) ? 0.f : gyp.y);
    gyp.x = gy0; gyp.y = gy1;
    float B0n = dpp_shl1(B.x);                             // next lane's col0
    float gx0 = hub(B.y - B.x, del);                       // col0->col1, in-register
    float gx1 = hub(B0n - B.y, del) * mR1;                 // col1->next col0; 0 at col 255
    float gx1p = dpp_shr1(gx1);                            // prev lane's gx1
    float divx0 = gx0 - gx1p * mL0;                        // div_x[0] = gx[0]
    float divx1 = gx1 - gx0;
    float2 o;
    o.x = B.x - 0.2f * (B.x - xnB.x - lam * (divx0 + divy0));
    o.y = B.y - 0.2f * (B.y - xnB.y - lam * (divx1 + divy1));
    return o;
}

__global__ __launch_bounds__(256, 5) void denoise_kernel(
        const float* __restrict__ x, const float* __restrict__ scale,
        uint2* __restrict__ arts, float* __restrict__ madsum,
        float4 lam4, float4 del4) {
    int lane = threadIdx.x & 63;
    int wave_id = blockIdx.x * 4 + (threadIdx.x >> 6);
    int img = wave_id / 48;          // 96 images
    int rem = wave_id - img * 48;
    int band = rem >> 4;             // 3 column bands (starts 0,116,232)
    int seg = rem & 15;              // 16 row segments x 16 rows
    int cb = band * 116;
    int c0 = cb + lane * 2, c1 = c0 + 1;
    int wlo = band ? cb + 6 : 0;     // 6-col margins absorb 3 stages of wave-edge garbage
    int whi = (band == 2) ? 255 : cb + 121;
    bool act = (c0 >= wlo) && (c0 <= whi);   // pair-uniform by construction
    bool ld = (c0 < 256);
    float mR1 = (c1 == 255) ? 0.f : 1.f;
    float mL0 = (c0 == 0) ? 0.f : 1.f;
    float sc = scale[img / 3];
    float inv_sc = 1.0f / sc;
    const float* xp = x + (size_t)img * 65536 + (ld ? c0 : 0);
    uint2* ap = arts + (size_t)img * 65536 + c0;

    float lam[4] = {lam4.x, lam4.y, lam4.z, lam4.w};
    float del[4] = {del4.x, del4.y, del4.z, del4.w};
    float2 z2 = make_float2(0.f, 0.f);
    float2 cur1[4], cur2[4], gyp1[4], gyp2[4], gyp3[4];
    #pragma unroll
    for (int v = 0; v < 4; ++v) { cur1[v]=z2; cur2[v]=z2; gyp1[v]=z2; gyp2[v]=z2; gyp3[v]=z2; }
    float2 n0 = z2, n1 = z2, n2 = z2;
    int out_lo = seg * 16, out_hi = out_lo + 15;
    int rs = (out_lo >= 3) ? out_lo - 3 : 0;   // 3-row pipeline warm-up
    int rend = out_hi + 3;                     // 3-step flush
    float msum = 0.f;

    float2 nl = z2;
    if (ld) { float2 v = *(const float2*)(xp + (rs << 8)); nl.x = v.x * inv_sc; nl.y = v.y * inv_sc; }
    for (int r = rs; r <= rend; ++r) {
        float2 nxt = z2;
        if (ld && r < rend && (r + 1) <= 255) nxt = *(const float2*)(xp + ((r + 1) << 8));
        int r1 = r - 1, r2 = r - 2, r3 = r - 3;
        float2 a[4];
        #pragma unroll
        for (int v = 0; v < 4; ++v) {
            float2 x1 = stage2(n0,      nl, n0, gyp1[v], r1, mR1, mL0, lam[v], del[v]);
            float2 x2 = stage2(cur1[v], x1, n1, gyp2[v], r2, mR1, mL0, lam[v], del[v]);
            float2 x3 = stage2(cur2[v], x2, n2, gyp3[v], r3, mR1, mL0, lam[v], del[v]);
            cur1[v] = x1; cur2[v] = x2; a[v] = x3;
        }
        if (r3 >= out_lo && act) {
            float a10 = a[0].x*sc, a20 = a[1].x*sc, a30 = a[2].x*sc, a40 = a[3].x*sc;
            float a11 = a[0].y*sc, a21 = a[1].y*sc, a31 = a[2].y*sc, a41 = a[3].y*sc;
            float a00 = n2.x*sc, a01 = n2.y*sc;
            uint4 pk;
            pk.x = packbf(a10, a20); pk.y = packbf(a30, a40);
            pk.z = packbf(a11, a21); pk.w = packbf(a31, a41);
            *(uint4*)(ap + ((size_t)r3 << 8)) = pk;
            float med0 = med5f(a00, a10, a20, a30, a40);
            float mad0 = med5f(fabsf(a00-med0), fabsf(a10-med0), fabsf(a20-med0),
                               fabsf(a30-med0), fabsf(a40-med0));
            float med1 = med5f(a01, a11, a21, a31, a41);
            float mad1 = med5f(fabsf(a01-med1), fabsf(a11-med1), fabsf(a21-med1),
                               fabsf(a31-med1), fabsf(a41-med1));
            msum += mad0 + mad1;
        }
        n2 = n1; n1 = n0; n0 = nl;
        nl.x = nxt.x * inv_sc; nl.y = nxt.y * inv_sc;
    }
    #pragma unroll
    for (int off = 32; off > 0; off >>= 1) msum += __shfl_down(msum, off);
    if (lane == 0) atomicAdd(madsum, msum);
}

// ---------------- fusion ----------------

__global__ __launch_bounds__(256) void fuse_kernel(
        const float* __restrict__ x, const uint2* __restrict__ arts,
        const float* __restrict__ madsum, float* __restrict__ out) {
    int i = blockIdx.x * 256 + threadIdx.x;
    float floorv = 0.1f * (*madsum) * (1.0f / 6291456.0f);
    uint2 pk = arts[i];
    float a0 = x[i];
    float a1 = __uint_as_float(pk.x << 16);
    float a2 = __uint_as_float(pk.x & 0xFFFF0000u);
    float a3 = __uint_as_float(pk.y << 16);
    float a4 = __uint_as_float(pk.y & 0xFFFF0000u);
    float med = med5f(a0, a1, a2, a3, a4);
    float d0 = fabsf(a0 - med), d1 = fabsf(a1 - med), d2 = fabsf(a2 - med);
    float d3 = fabsf(a3 - med), d4 = fabsf(a4 - med);
    float mad = med5f(d0, d1, d2, d3, d4);
    float m = fmaxf(mad, floorv);
    float inv = 0.5f / m;
    float w0 = __expf(-d0 * inv), w1 = __expf(-d1 * inv), w2 = __expf(-d2 * inv);
    float w3 = __expf(-d3 * inv), w4 = __expf(-d4 * inv);
    float swt = w0 + w1 + w2 + w3 + w4;
    float sva = fmaf(w0, a0, fmaf(w1, a1, fmaf(w2, a2, fmaf(w3, a3, w4 * a4))));
    out[i] = sva / (swt + 1e-8f);
}

// ---------------- launch ----------------

extern "C" void kernel_launch(void* const* d_in, const int* in_sizes, int n_in,
                              void* d_out, int out_size, void* d_ws, size_t ws_size,
                              hipStream_t stream) {
    const float* x = (const float*)d_in[0];
    float* out = (float*)d_out;
    char* ws = (char*)d_ws;
    float* madsum  = (float*)ws;
    u32* done16    = (u32*)(ws + 128);
    u32* prefix12  = (u32*)(ws + 256);
    u32* kk2       = (u32*)(ws + 384);
    float* scale   = (float*)(ws + 512);
    u32* cnt       = (u32*)(ws + 1024);
    u32* gh        = (u32*)(ws + 8192);
    u32* buf       = (u32*)(ws + 270336);
    uint2* arts    = (uint2*)(ws + 1843200);

    hipMemsetAsync(ws, 0, 270336, stream);   // control + 256 KB histogram

    histA_kernel<<<768, 256, 0, stream>>>(x, gh, done16, prefix12, kk2);
    compactB_kernel<<<768, 256, 0, stream>>>(x, prefix12, cnt, buf);
    selectC_kernel<<<32, 256, 0, stream>>>(cnt, buf, prefix12, kk2, scale);

    float lamf[4], delf[4];
    for (int i = 0; i < 4; ++i) {
        double lam = 0.025 + 0.05 * (double)i / 3.0;
        lamf[i] = (float)lam;
        delf[i] = (float)(0.01 * sqrt(lam / (0.05 + 1e-8)));
    }
    float4 lam4 = make_float4(lamf[0], lamf[1], lamf[2], lamf[3]);
    float4 del4 = make_float4(delf[0], delf[1], delf[2], delf[3]);

    denoise_kernel<<<1152, 256, 0, stream>>>(x, scale, arts, madsum, lam4, del4);
    fuse_kernel<<<24576, 256, 0, stream>>>(x, arts, madsum, out);
}